// Round 11
// baseline (166.049 us; speedup 1.0000x reference)
//
#include <hip/hip_runtime.h>

// Problem constants: N=500000, C=128, R=4 (C/R=32), B=32.
#define C 128
#define CR 32
#define B 32
#define RPB 1024                     // rows per tile (489 tiles at N=500000)

typedef float f32x4 __attribute__((ext_vector_type(4)));

__device__ inline int lower_bound_i(const int* __restrict__ a, int n, int key) {
    int lo = 0, hi = n;
    while (lo < hi) {
        int mid = (lo + hi) >> 1;
        if (a[mid] < key) lo = mid + 1; else hi = mid;
    }
    return lo;
}

// ---------------------------------------------------------------------------
// Kernel 1: per-tile DUAL-SLOT partial sums (slot logic proven in R9).
// 512 thr = 32 f32x4-cols x 16 row-lanes, 64 rows/lane, 8-deep load pipeline.
// Single-segment tiles -> slot0. Boundary tiles (exactly 2 segs; segments
// ~15625 rows >> RPB): find the split point, run TWO clean pipelined streams
// -> slot0 (first seg) + slot1 (second seg). No atomics, no init required:
// kernel 2 reads exactly the slots written here.
// ---------------------------------------------------------------------------
__global__ __launch_bounds__(512, 4) void seg_partial_kernel(
    const f32x4* __restrict__ x4, const int* __restrict__ batch,
    f32x4* __restrict__ partial4, int N)
{
    const int t  = threadIdx.x;
    const int c4 = t & 31;                 // f32x4 column group 0..31
    const int rl = t >> 5;                 // row lane 0..15
    const long base = (long)blockIdx.x * RPB;
    long rend = base + RPB;
    if (rend > N) rend = N;
    const int segA = batch[base];
    const int segB = batch[rend - 1];

    __shared__ f32x4 s_redA[16][32];
    __shared__ f32x4 s_redB[16][32];

    if (segA == segB) {
        // ---- fast path: one clean 8-deep stream ----
        const f32x4* p = x4 + (base + rl) * 32 + c4;
        long r = base + rl;
        f32x4 a0 = (f32x4)(0.f), a1 = (f32x4)(0.f);
        f32x4 a2 = (f32x4)(0.f), a3 = (f32x4)(0.f);
        while (r + 112 < rend) {           // 8 rows (stride 16) per iter
            f32x4 v0 = p[0 * 512];
            f32x4 v1 = p[1 * 512];
            f32x4 v2 = p[2 * 512];
            f32x4 v3 = p[3 * 512];
            f32x4 v4 = p[4 * 512];
            f32x4 v5 = p[5 * 512];
            f32x4 v6 = p[6 * 512];
            f32x4 v7 = p[7 * 512];
            a0 += v0; a1 += v1; a2 += v2; a3 += v3;
            a0 += v4; a1 += v5; a2 += v6; a3 += v7;
            r += 128; p += 8 * 512;
        }
        while (r < rend) { a0 += p[0]; r += 16; p += 512; }
        f32x4 acc = (a0 + a1) + (a2 + a3);

        s_redA[rl][c4] = acc;
        __syncthreads();
        if (t < 32) {
            f32x4 s = s_redA[0][t];
            #pragma unroll
            for (int i = 1; i < 16; ++i) s += s_redA[i][t];
            partial4[(long)blockIdx.x * 64 + t] = s;        // slot0
        }
    } else {
        // ---- boundary tile: split point, two clean streams ----
        // m = first row of segB within [base, rend)
        long mlo = base, mhi = rend - 1;
        while (mlo < mhi) {                // uniform binary search
            long mid = (mlo + mhi) >> 1;
            if (batch[mid] < segB) mlo = mid + 1; else mhi = mid;
        }
        const long m = mlo;

        f32x4 aA = (f32x4)(0.f), aB = (f32x4)(0.f);
        for (long r = base + rl; r < m; r += 16)
            aA += x4[r * 32 + c4];
        for (long r = m + rl; r < rend; r += 16)
            aB += x4[r * 32 + c4];

        s_redA[rl][c4] = aA;
        s_redB[rl][c4] = aB;
        __syncthreads();
        if (t < 32) {
            f32x4 sA = s_redA[0][t], sB = s_redB[0][t];
            #pragma unroll
            for (int i = 1; i < 16; ++i) { sA += s_redA[i][t]; sB += s_redB[i][t]; }
            partial4[(long)blockIdx.x * 64 + t]      = sA;  // slot0: first seg
            partial4[(long)blockIdx.x * 64 + 32 + t] = sB;  // slot1: second seg
        }
    }
}

// ---------------------------------------------------------------------------
// Kernel 2: gate + scale, ONE dispatch. Every block redundantly recomputes
// attn in a short prologue (partials are 250 KB, L2-broadcast across blocks):
//   bounds (33 binary searches) -> per-seg fold of tile partials (8 seg-lanes
//   x 32 col-groups, 4-deep unroll) -> avg -> MLP fully in LDS -> s_attn.
// Then grid-stride broadcast multiply with NT stores, attn read from LDS.
// ---------------------------------------------------------------------------
__global__ __launch_bounds__(256, 8) void gate_scale_kernel(
    const f32x4* __restrict__ x4, const int* __restrict__ batch,
    const f32x4* __restrict__ partial4,
    const float* __restrict__ W1, const float* __restrict__ b1,
    const float* __restrict__ W2, const float* __restrict__ b2,
    f32x4* __restrict__ out4, int N)
{
    const int t  = threadIdx.x;
    const int c4 = t & 31;                 // f32x4 column group 0..31
    const int sl = t >> 5;                 // seg lane 0..7

    __shared__ int   s_bnd[B + 1];
    __shared__ f32x4 s_buf4[B][32];        // avg, then attn (16 KB)
    __shared__ float s_h[B][CR];           // 4 KB
    float* s_buf = (float*)s_buf4;

    if (t <= B) s_bnd[t] = lower_bound_i(batch, N, t);
    __syncthreads();

    // fold: lane (sl,c4) owns segs sl, sl+8, sl+16, sl+24
    for (int s = sl; s < B; s += 8) {
        const int lo = s_bnd[s], hi = s_bnd[s + 1];
        f32x4 acc = (f32x4)(0.f);
        if (lo < hi) {
            const int t0 = lo / RPB;
            const int t1 = (hi - 1) / RPB;
            int tt = t0;
            if ((lo % RPB) != 0) {         // head tile is boundary -> slot1
                acc += partial4[(long)tt * 64 + 32 + c4];
                ++tt;
            }
            for (; tt + 3 <= t1; tt += 4) {            // 4-deep pipelined
                f32x4 u0 = partial4[(long)(tt + 0) * 64 + c4];
                f32x4 u1 = partial4[(long)(tt + 1) * 64 + c4];
                f32x4 u2 = partial4[(long)(tt + 2) * 64 + c4];
                f32x4 u3 = partial4[(long)(tt + 3) * 64 + c4];
                acc += u0; acc += u1; acc += u2; acc += u3;
            }
            for (; tt <= t1; ++tt)
                acc += partial4[(long)tt * 64 + c4];
        }
        const float inv = 1.0f / fmaxf((float)(hi - lo), 1.0f);
        s_buf[s * C + c4 * 4 + 0] = acc.x * inv;
        s_buf[s * C + c4 * 4 + 1] = acc.y * inv;
        s_buf[s * C + c4 * 4 + 2] = acc.z * inv;
        s_buf[s * C + c4 * 4 + 3] = acc.w * inv;
    }
    __syncthreads();

    // h = relu(avg @ W1 + b1): 1024 outputs, 4 per thread
    for (int k = t; k < B * CR; k += 256) {
        int s = k >> 5, j = k & (CR - 1);
        float d = b1[j];
        #pragma unroll 8
        for (int c = 0; c < C; ++c)
            d += s_buf[s * C + c] * W1[c * CR + j];
        s_h[s][j] = fmaxf(d, 0.f);
    }
    __syncthreads();

    // attn = sigmoid(h @ W2 + b2): 4096 outputs, 16/thread; overwrite s_buf
    for (int k = t; k < B * C; k += 256) {
        int s = k >> 7, c = k & (C - 1);
        float d = b2[c];
        #pragma unroll
        for (int j = 0; j < CR; ++j)
            d += s_h[s][j] * W2[j * C + c];
        s_buf[s * C + c] = 1.0f / (1.0f + expf(-d));
    }
    __syncthreads();

    // streaming: out = x * attn[batch[row]] (attn in LDS, NT stores)
    const long total4 = (long)N * 32;
    long idx = (long)blockIdx.x * 256 + t;
    const long stride = (long)gridDim.x * 256;
    for (; idx < total4; idx += stride) {
        long row = idx >> 5;
        int  cc  = (int)(idx & 31);
        int  b   = batch[row];
        f32x4 o = x4[idx] * s_buf4[b][cc];
        __builtin_nontemporal_store(o, &out4[idx]);
    }
}

extern "C" void kernel_launch(void* const* d_in, const int* in_sizes, int n_in,
                              void* d_out, int out_size, void* d_ws, size_t ws_size,
                              hipStream_t stream) {
    const float* x     = (const float*)d_in[0];
    const int*   batch = (const int*)d_in[1];
    // d_in[2] = batch_num scalar (known = 32, compile-time B)
    const float* W1 = (const float*)d_in[3];
    const float* b1 = (const float*)d_in[4];
    const float* W2 = (const float*)d_in[5];
    const float* b2 = (const float*)d_in[6];
    float* out = (float*)d_out;

    const int N = in_sizes[0] / C;
    const int ntiles = (N + RPB - 1) / RPB;

    // ws layout: partial[ntiles][2][C] floats (~500 KB)
    f32x4* partial = (f32x4*)d_ws;

    seg_partial_kernel<<<ntiles, 512, 0, stream>>>((const f32x4*)x, batch,
                                                   partial, N);

    gate_scale_kernel<<<1024, 256, 0, stream>>>((const f32x4*)x, batch,
                                                (const f32x4*)partial,
                                                W1, b1, W2, b2,
                                                (f32x4*)out, N);
}

// Round 12
// 132.112 us; speedup vs baseline: 1.2569x; 1.2569x over previous
//
#include <hip/hip_runtime.h>
#include <hip/hip_bf16.h>

// Problem constants: N=500000, C=128, R=4 (C/R=32), B=32.
// R12 = exact revert to the R7 champion (134.2 us): 3 kernels, no atomics,
// no init, no coop. Ledger of rejected alternatives:
//   R9  coop grid.sync fusion: 396 us (occupancy halved, coop sync cost)
//   R10 RPB=128 + bigger scale grid: 136 us (neutral)
//   R11 2-kernel redundant gate prologue: 166 us (serial bsearch + cross-XCD
//       partial reads in every block)
#define C 128
#define CR 32
#define B 32
#define RPB 256                       // rows per tile in the partial-sum pass

typedef float f32x4 __attribute__((ext_vector_type(4)));

__device__ inline int lower_bound_i(const int* __restrict__ a, int n, int key) {
    int lo = 0, hi = n;
    while (lo < hi) {
        int mid = (lo + hi) >> 1;
        if (a[mid] < key) lo = mid + 1; else hi = mid;
    }
    return lo;
}

// ---------------------------------------------------------------------------
// Kernel 1: per-block partial sums. NO atomics, NO global init required.
// 256 thr = 32 float4-column-groups x 8 row-lanes. Single-segment blocks
// (batch sorted -> all but ~31 of 1954) accumulate with an 8-deep explicit
// load pipeline, LDS-reduce the 8 row-lanes, write partial[block][C] with
// plain stores. Multi-segment blocks exit; kernel 2 re-reads their rows.
// ---------------------------------------------------------------------------
__global__ __launch_bounds__(256) void seg_partial_kernel(
    const f32x4* __restrict__ x4, const int* __restrict__ batch,
    f32x4* __restrict__ partial4, int N)
{
    const int t  = threadIdx.x;
    const int c4 = t & 31;                 // float4 column group 0..31
    const int rl = t >> 5;                 // row lane 0..7
    const long base = (long)blockIdx.x * RPB;
    long rend = base + RPB;
    if (rend > N) rend = N;

    if (batch[base] != batch[rend - 1]) return;   // boundary block: skip

    const f32x4* p = x4 + (base + rl) * 32 + c4;
    long r = base + rl;
    f32x4 a0 = (f32x4)(0.f), a1 = (f32x4)(0.f);
    f32x4 a2 = (f32x4)(0.f), a3 = (f32x4)(0.f);
    while (r + 56 < rend) {                // 8 strided rows per iteration
        f32x4 v0 = p[0 * 256];
        f32x4 v1 = p[1 * 256];
        f32x4 v2 = p[2 * 256];
        f32x4 v3 = p[3 * 256];
        f32x4 v4 = p[4 * 256];
        f32x4 v5 = p[5 * 256];
        f32x4 v6 = p[6 * 256];
        f32x4 v7 = p[7 * 256];
        a0 += v0; a1 += v1; a2 += v2; a3 += v3;
        a0 += v4; a1 += v5; a2 += v6; a3 += v7;
        r += 64; p += 8 * 256;
    }
    while (r < rend) { a0 += p[0]; r += 8; p += 256; }
    f32x4 acc = (a0 + a1) + (a2 + a3);

    __shared__ f32x4 s_red[8][32];
    s_red[rl][c4] = acc;
    __syncthreads();
    if (t < 32) {
        f32x4 s = s_red[0][t];
        #pragma unroll
        for (int i = 1; i < 8; ++i) s += s_red[i][t];
        partial4[(long)blockIdx.x * 32 + t] = s;
    }
}

// ---------------------------------------------------------------------------
// Kernel 2: one block per segment, 1024 thr = 32 f32x4-col-groups x 32
// row-lanes. Binary-search batch for [lo,hi); fold full-block partials +
// head/tail rows of x (vectorized, 32-lane-strided), LDS-reduce, then the
// SE gate MLP in-block: h = relu(avg@W1+b1), attn = sigmoid(h@W2+b2).
// Plain stores, deterministic, no init needed.
// ---------------------------------------------------------------------------
__global__ __launch_bounds__(1024) void reduce_mlp_kernel(
    const f32x4* __restrict__ x4, const int* __restrict__ batch,
    const f32x4* __restrict__ partial4,
    const float* __restrict__ W1, const float* __restrict__ b1,
    const float* __restrict__ W2, const float* __restrict__ b2,
    float* __restrict__ attn, int N)
{
    const int seg = blockIdx.x;
    const int t   = threadIdx.x;
    const int c4  = t & 31;                // float4 column group 0..31
    const int rl  = t >> 5;                // row lane 0..31

    const int lo = lower_bound_i(batch, N, seg);       // uniform (broadcast)
    const int hi = lower_bound_i(batch, N, seg + 1);

    f32x4 acc = (f32x4)(0.f);
    const int fb0 = (lo + RPB - 1) / RPB;              // first fully-inside block
    const int fb1 = hi / RPB;                          // one past last fully-inside
    if (fb0 < fb1) {
        for (int blk = fb0 + rl; blk < fb1; blk += 32)         // ~61/32 iters
            acc += partial4[(long)blk * 32 + c4];
        #pragma unroll 4
        for (long r = lo + rl; r < (long)fb0 * RPB; r += 32)   // head (<RPB rows)
            acc += x4[r * 32 + c4];
        #pragma unroll 4
        for (long r = (long)fb1 * RPB + rl; r < hi; r += 32)   // tail (<RPB rows)
            acc += x4[r * 32 + c4];
    } else {
        #pragma unroll 4
        for (long r = lo + rl; r < hi; r += 32)                // tiny segment
            acc += x4[r * 32 + c4];
    }

    __shared__ f32x4 s_red[32][32];
    __shared__ float s_avg[C];
    __shared__ float s_h[CR];
    s_red[rl][c4] = acc;
    __syncthreads();
    if (t < 32) {
        f32x4 s = s_red[0][t];
        #pragma unroll
        for (int i = 1; i < 32; ++i) s += s_red[i][t];
        float inv = 1.0f / fmaxf((float)(hi - lo), 1.0f);
        s_avg[4 * t + 0] = s.x * inv;
        s_avg[4 * t + 1] = s.y * inv;
        s_avg[4 * t + 2] = s.z * inv;
        s_avg[4 * t + 3] = s.w * inv;
    }
    __syncthreads();
    if (t < CR) {                           // h = relu(avg @ W1 + b1)
        float d = b1[t];
        #pragma unroll 8
        for (int c = 0; c < C; ++c)
            d += s_avg[c] * W1[c * CR + t]; // W1 row: 32 consecutive -> coalesced
        s_h[t] = fmaxf(d, 0.f);
    }
    __syncthreads();
    if (t < C) {                            // attn = sigmoid(h @ W2 + b2)
        float d = b2[t];
        #pragma unroll
        for (int j = 0; j < CR; ++j)
            d += s_h[j] * W2[j * C + t];    // W2 row: 128 consecutive -> coalesced
        attn[seg * C + t] = 1.0f / (1.0f + expf(-d));
    }
}

// ---------------------------------------------------------------------------
// Kernel 3: out[n][c] = x[n][c] * attn[batch[n]][c]. NT stores keep out from
// polluting L3 so x (244 MiB) stays L3-resident across replays (replay
// counters: hbm_bytes ~= WRITE only). attn (16KB) is L1-resident.
// ---------------------------------------------------------------------------
__global__ __launch_bounds__(256) void scale_kernel(
    const f32x4* __restrict__ x4, const int* __restrict__ batch,
    const f32x4* __restrict__ attn4, f32x4* __restrict__ out4,
    long total4)
{
    long idx    = (long)blockIdx.x * blockDim.x + threadIdx.x;
    long stride = (long)gridDim.x * blockDim.x;
    for (; idx < total4; idx += stride) {
        long row = idx >> 5;                 // C/4 = 32 float4 per row
        int  c4  = (int)(idx & 31);
        int  b   = batch[row];
        f32x4 o = x4[idx] * attn4[b * 32 + c4];
        __builtin_nontemporal_store(o, &out4[idx]);
    }
}

extern "C" void kernel_launch(void* const* d_in, const int* in_sizes, int n_in,
                              void* d_out, int out_size, void* d_ws, size_t ws_size,
                              hipStream_t stream) {
    const float* x     = (const float*)d_in[0];
    const int*   batch = (const int*)d_in[1];
    // d_in[2] = batch_num scalar (known = 32, compile-time B)
    const float* W1 = (const float*)d_in[3];
    const float* b1 = (const float*)d_in[4];
    const float* W2 = (const float*)d_in[5];
    const float* b2 = (const float*)d_in[6];
    float* out = (float*)d_out;

    const int N = in_sizes[0] / C;
    const int ntiles = (N + RPB - 1) / RPB;

    // ws layout (floats): attn[B*C] | partial[ntiles*C]  (~1.0 MB)
    float* attn    = (float*)d_ws;
    float* partial = attn + B * C;

    seg_partial_kernel<<<ntiles, 256, 0, stream>>>((const f32x4*)x, batch,
                                                   (f32x4*)partial, N);

    reduce_mlp_kernel<<<B, 1024, 0, stream>>>((const f32x4*)x, batch,
                                              (const f32x4*)partial,
                                              W1, b1, W2, b2, attn, N);

    const long total4 = (long)N * 32;
    scale_kernel<<<2048, 256, 0, stream>>>((const f32x4*)x, batch,
                                           (const f32x4*)attn, (f32x4*)out,
                                           total4);
}